// Round 7
// baseline (1004.110 us; speedup 1.0000x reference)
//
#include <hip/hip_runtime.h>
#include <hip/hip_bf16.h>

#define N_USER 200000
#define N_ITEM 100000
#define N_NODES 300000
#define EMB 80
#define FEAT 16
#define NL 3
#define NNZ 1000000
#define BATCH 4096
#define OUTW 320

typedef __bf16 bf16x8 __attribute__((ext_vector_type(8)));
typedef float f32x4 __attribute__((ext_vector_type(4)));

__device__ __forceinline__ unsigned short f2bf(float f){
  union { float f; unsigned int i; } x; x.f = f;
  unsigned int i = x.i;
  unsigned int r = i + 0x7fff + ((i >> 16) & 1u);
  return (unsigned short)(r >> 16);
}

// ---- diagnostic fill ----
__global__ void k_fill(float* out, int n, float v){
  int i = blockIdx.x * blockDim.x + threadIdx.x;
  if (i < n) out[i] = v;
}

// ---- winner: last write wins for duplicate u_id ----
__global__ void k_winner(const int* __restrict__ u_id, int* __restrict__ winner){
  int b = blockIdx.x * blockDim.x + threadIdx.x;
  if (b >= BATCH) return;
  atomicMax(&winner[u_id[b]], b);
}

// ---- E = concat(user_tab, item_tab), float4 ----
__global__ void k_copy4(const float4* __restrict__ user_tab, const float4* __restrict__ item_tab,
                        float4* __restrict__ E){
  int idx = blockIdx.x * blockDim.x + threadIdx.x;
  if (idx >= N_NODES*EMB/4) return;
  E[idx] = (idx < N_USER*EMB/4) ? user_tab[idx] : item_tab[idx - N_USER*EMB/4];
}

// ---- blended scatter: E[u_id[b]] = 0.5*(user_tab[u]+feat[b]) for winning b ----
__global__ void k_scatter_blend(const int* __restrict__ u_id, const int* __restrict__ winner,
                        const int* __restrict__ age, const int* __restrict__ sex,
                        const int* __restrict__ month, const int* __restrict__ day,
                        const int* __restrict__ dow,
                        const float* __restrict__ user_tab,
                        const float* __restrict__ age_tab, const float* __restrict__ sex_tab,
                        const float* __restrict__ month_tab, const float* __restrict__ day_tab,
                        const float* __restrict__ dow_tab,
                        float* __restrict__ E){
  int idx = blockIdx.x * blockDim.x + threadIdx.x;
  if (idx >= BATCH*EMB) return;
  int b = idx / EMB;
  int c = idx - b*EMB;
  int u = u_id[b];
  if (winner[u] != b) return;
  int t = c >> 4, cc = c & 15;
  int key; const float* tab;
  switch (t){
    case 0: key = age[b];   tab = age_tab;   break;
    case 1: key = sex[b];   tab = sex_tab;   break;
    case 2: key = month[b]; tab = month_tab; break;
    case 3: key = day[b];   tab = day_tab;   break;
    default: key = dow[b];  tab = dow_tab;   break;
  }
  float f = tab[key*FEAT + cc];
  E[(size_t)u*EMB + c] = 0.5f * user_tab[(size_t)u*EMB + c] + 0.5f * f;
}

// ---- prep: Wt[i][n][k] = stacked [W1;W2]^T (bf16, n-major), biasf = 2*b1+b2 ----
__global__ void k_prep(const float* __restrict__ W1, const float* __restrict__ W2,
                       const float* __restrict__ b1, const float* __restrict__ b2,
                       unsigned short* __restrict__ Wt, float* __restrict__ biasf){
  int idx = blockIdx.x * blockDim.x + threadIdx.x;
  if (idx < NL*EMB*160){
    int i = idx / (EMB*160);
    int rem = idx - i*(EMB*160);
    int n = rem / 160;
    int k = rem - n*160;
    float v = (k < EMB) ? W1[i*EMB*EMB + k*EMB + n] : W2[i*EMB*EMB + (k-EMB)*EMB + n];
    Wt[idx] = f2bf(v);
  } else if (idx < NL*EMB*160 + NL*EMB){
    int t = idx - NL*EMB*160;
    biasf[t] = 2.0f * b1[t] + b2[t];
  }
}

// ================= CSR build =================
__global__ void k_hist(const int* __restrict__ rows, int* __restrict__ cnt){
  int e = blockIdx.x * blockDim.x + threadIdx.x;
  if (e < NNZ) atomicAdd(&cnt[rows[e]], 1);
}

#define SCAN_BLK 1024
__global__ void k_scan1(int* __restrict__ cnt, int* __restrict__ bsum){
  __shared__ int s[256];
  int tid = threadIdx.x;
  int base = blockIdx.x * SCAN_BLK + tid*4;
  int v[4]; int sum = 0;
  #pragma unroll
  for (int j = 0; j < 4; j++){
    int i = base + j;
    v[j] = (i < N_NODES) ? cnt[i] : 0;
    sum += v[j];
  }
  s[tid] = sum; __syncthreads();
  int own = sum;
  for (int d = 1; d < 256; d <<= 1){
    int t = (tid >= d) ? s[tid-d] : 0;
    __syncthreads();
    s[tid] += t;
    __syncthreads();
  }
  int excl = s[tid] - own;
  if (tid == 0) bsum[blockIdx.x] = s[255];
  int run = excl;
  #pragma unroll
  for (int j = 0; j < 4; j++){
    int i = base + j;
    if (i < N_NODES) cnt[i] = run;
    run += v[j];
  }
}

#define NSCAN_BLOCKS ((N_NODES + SCAN_BLK - 1)/SCAN_BLK)   // 293
__global__ void k_scan2(int* __restrict__ bsum){
  __shared__ int s[512];
  int tid = threadIdx.x;
  int v = (tid < NSCAN_BLOCKS) ? bsum[tid] : 0;
  s[tid] = v; __syncthreads();
  for (int d = 1; d < 512; d <<= 1){
    int t = (tid >= d) ? s[tid-d] : 0;
    __syncthreads();
    s[tid] += t;
    __syncthreads();
  }
  if (tid < NSCAN_BLOCKS) bsum[tid] = s[tid] - v;
}

__global__ void k_scan3(int* __restrict__ rowptr, const int* __restrict__ bsum,
                        int* __restrict__ cursor){
  int i = blockIdx.x * blockDim.x + threadIdx.x;
  if (i >= N_NODES) return;
  int v = rowptr[i] + bsum[i >> 10];
  rowptr[i] = v;
  cursor[i] = v;
  if (i == 0) rowptr[N_NODES] = NNZ;
}

__global__ void k_scatter_edges(const int* __restrict__ rows, const int* __restrict__ cols,
                                const float* __restrict__ vals,
                                int* __restrict__ cursor,
                                int* __restrict__ cols_s, float* __restrict__ vals_s){
  int e = blockIdx.x * blockDim.x + threadIdx.x;
  if (e >= NNZ) return;
  int r = rows[e];
  int pos = atomicAdd(&cursor[r], 1);
  cols_s[pos] = cols[e];
  vals_s[pos] = vals[e];
}

// ==== fused layer: LE = L@Ein (CSR, LDS); Eout = leaky([Ein+LE|Ein*LE]@[W1;W2]+2b1+b2) ====
#define XSTRIDE 168
#define LE_STRIDE 81
__launch_bounds__(256)
__global__ void k_fused(const float* __restrict__ Ein, float* __restrict__ Eout,
                        const int* __restrict__ rowptr, const int* __restrict__ cols_s,
                        const float* __restrict__ vals_s,
                        const unsigned short* __restrict__ Wt, const float* __restrict__ biasf){
  __shared__ float le[64 * LE_STRIDE];        // 20736 B
  __shared__ unsigned short xs[64 * XSTRIDE]; // 21504 B
  int tid = threadIdx.x;
  long row0 = (long)blockIdx.x * 64;

  // phase 1: SpMM rows into LDS (20 float4-lanes per row, 5 units/thread)
  for (int u = tid; u < 64*20; u += 256){
    int lr = u / 20, q = u - lr*20;
    long r = row0 + lr;
    float4 acc = {0.f,0.f,0.f,0.f};
    if (r < N_NODES){
      int s = rowptr[r], e = rowptr[r+1];
      for (int i = s; i < e; i++){
        int c = cols_s[i];
        float v = vals_s[i];
        const float4 ev = *(const float4*)(Ein + (size_t)c*EMB + q*4);
        acc.x += v*ev.x; acc.y += v*ev.y; acc.z += v*ev.z; acc.w += v*ev.w;
      }
    }
    float* d = le + lr*LE_STRIDE + q*4;
    d[0]=acc.x; d[1]=acc.y; d[2]=acc.z; d[3]=acc.w;
  }

  // B fragments (global, independent of LDS) — issue early
  int lane = tid & 63;
  int wave = tid >> 6;
  int m = lane & 15;
  int quad = lane >> 4;
  bf16x8 bfrag[5][5];
  #pragma unroll
  for (int nt = 0; nt < 5; nt++)
    #pragma unroll
    for (int kt = 0; kt < 5; kt++)
      bfrag[nt][kt] = *(const bf16x8*)(Wt + (nt*16 + m)*160 + kt*32 + quad*8);

  __syncthreads();

  // phase 2: xs = bf16([Ein+LE | Ein*LE])
  for (int p = tid; p < 64*80; p += 256){
    int lr = p / 80, pp = p - lr*80;
    long r = row0 + lr;
    unsigned int o = 0;
    if (r < N_NODES){
      int k = 2*pp;
      int c = (k < EMB) ? k : (k - EMB);
      const float2 ee = *(const float2*)(Ein + r*EMB + c);
      float l0 = le[lr*LE_STRIDE + c];
      float l1 = le[lr*LE_STRIDE + c + 1];
      float x0, x1;
      if (k < EMB){ x0 = ee.x + l0; x1 = ee.y + l1; }
      else        { x0 = ee.x * l0; x1 = ee.y * l1; }
      o = (unsigned int)f2bf(x0) | ((unsigned int)f2bf(x1) << 16);
    }
    *(unsigned int*)&xs[lr*XSTRIDE + 2*pp] = o;
  }
  __syncthreads();

  f32x4 acc[5];
  #pragma unroll
  for (int nt = 0; nt < 5; nt++) acc[nt] = (f32x4){0.f,0.f,0.f,0.f};

  int arow = wave*16 + m;
  #pragma unroll
  for (int kt = 0; kt < 5; kt++){
    bf16x8 af = *(const bf16x8*)&xs[arow*XSTRIDE + kt*32 + quad*8];
    #pragma unroll
    for (int nt = 0; nt < 5; nt++)
      acc[nt] = __builtin_amdgcn_mfma_f32_16x16x32_bf16(af, bfrag[nt][kt], acc[nt], 0, 0, 0);
  }

  // epilogue: C/D layout col=lane&15, row=quad*4+reg
  long rbase = row0 + wave*16 + quad*4;
  #pragma unroll
  for (int nt = 0; nt < 5; nt++){
    int col = nt*16 + m;
    float b = biasf[col];
    #pragma unroll
    for (int i = 0; i < 4; i++){
      long r = rbase + i;
      if (r < N_NODES){
        float v = acc[nt][i] + b;
        Eout[r*EMB + col] = (v > 0.f) ? v : 0.2f * v;
      }
    }
  }
}

// ---- fused gather + row L2 norm (wave per gathered row), fp32 out ----
__global__ void k_gather_wave(const float* __restrict__ E, const int* __restrict__ u_id,
                              const int* __restrict__ pos, const int* __restrict__ neg,
                              float* __restrict__ out, int layer, int do_norm){
  int gw = blockIdx.x * (blockDim.x >> 6) + (threadIdx.x >> 6);
  if (gw >= 3*BATCH) return;
  int lane = threadIdx.x & 63;
  int chunk = gw / BATCH;
  int b = gw - chunk*BATCH;
  int node = (chunk == 0) ? u_id[b] : ((chunk == 1) ? N_USER + pos[b] : N_USER + neg[b]);
  const float* er = E + (size_t)node*EMB;
  float v0 = er[lane];
  float v1 = (lane < EMB-64) ? er[64 + lane] : 0.f;
  float scale = 1.f;
  if (do_norm){
    float ss = v0*v0 + v1*v1;
    #pragma unroll
    for (int s = 32; s > 0; s >>= 1) ss += __shfl_xor(ss, s, 64);
    float nrm = fmaxf(sqrtf(ss), 1e-12f);
    scale = 1.f / nrm;
  }
  float* po = out + (size_t)chunk*BATCH*OUTW + (size_t)b*OUTW + layer*EMB;
  po[lane] = v0 * scale;
  if (lane < EMB-64) po[64 + lane] = v1 * scale;
}

extern "C" void kernel_launch(void* const* d_in, const int* in_sizes, int n_in,
                              void* d_out, int out_size, void* d_ws, size_t ws_size,
                              hipStream_t stream) {
  float* out = (float*)d_out;

  // workspace layout (identical footprint to R6's proven-fitting layout)
  const size_t OFF_E0     = 0;                   // 96,000,000
  const size_t OFF_E1     = 96000000;            // 96,000,000
  const size_t OFF_ROWPTR = 192000000;           // 1,200,640
  const size_t OFF_CURSOR = 193200640;           // 1,200,640
  const size_t OFF_COLS   = 194401280;           // 4,000,000
  const size_t OFF_VALS   = 198401280;           // 4,000,000
  const size_t OFF_BSUM   = 202401280;           // 4,096
  const size_t OFF_WT     = 202405376;           // 76,800
  const size_t OFF_BIAS   = 202482176;           // 1,024
  const size_t OFF_WIN    = 202483200;           // 800,000
  const size_t NEED       = 203283200;

  float code = 0.f;
  if (ws_size < NEED)                      code = 7.f;
  else if (n_in != 22)                     code = 9.f;
  else if (in_sizes[0] != BATCH)           code = 11.f;
  else if (in_sizes[10] != NNZ)            code = 13.f;
  else if (out_size != 3*BATCH*OUTW)       code = 19.f;
  if (code != 0.f){
    k_fill<<<(out_size + 255)/256, 256, 0, stream>>>(out, out_size, code);
    return;
  }

  const int* u_id  = (const int*)d_in[0];
  const int* age   = (const int*)d_in[1];
  const int* sex   = (const int*)d_in[2];
  const int* month = (const int*)d_in[3];
  const int* day   = (const int*)d_in[4];
  const int* dow   = (const int*)d_in[5];
  const int* pos   = (const int*)d_in[6];
  const int* neg   = (const int*)d_in[7];
  const int* lrows = (const int*)d_in[8];
  const int* lcols = (const int*)d_in[9];
  const float* lvals    = (const float*)d_in[10];
  const float* user_tab = (const float*)d_in[11];
  const float* item_tab = (const float*)d_in[12];
  const float* age_tab  = (const float*)d_in[13];
  const float* sex_tab  = (const float*)d_in[14];
  const float* month_tab= (const float*)d_in[15];
  const float* day_tab  = (const float*)d_in[16];
  const float* dow_tab  = (const float*)d_in[17];
  const float* W1 = (const float*)d_in[18];
  const float* b1 = (const float*)d_in[19];
  const float* W2 = (const float*)d_in[20];
  const float* b2 = (const float*)d_in[21];

  char* ws = (char*)d_ws;
  float* E0     = (float*)(ws + OFF_E0);
  float* E1     = (float*)(ws + OFF_E1);
  int* rowptr   = (int*)(ws + OFF_ROWPTR);
  int* cursor   = (int*)(ws + OFF_CURSOR);
  int* cols_s   = (int*)(ws + OFF_COLS);
  float* vals_s = (float*)(ws + OFF_VALS);
  int* bsum     = (int*)(ws + OFF_BSUM);
  unsigned short* Wt = (unsigned short*)(ws + OFF_WT);
  float* biasf  = (float*)(ws + OFF_BIAS);
  int* winner   = (int*)(ws + OFF_WIN);

  // ---- prologue: build E0 ----
  hipMemsetAsync(winner, 0xFF, N_USER*sizeof(int), stream);
  k_winner<<<(BATCH+255)/256, 256, 0, stream>>>(u_id, winner);
  k_copy4<<<(N_NODES*EMB/4+255)/256, 256, 0, stream>>>((const float4*)user_tab, (const float4*)item_tab, (float4*)E0);
  k_scatter_blend<<<(BATCH*EMB+255)/256, 256, 0, stream>>>(u_id, winner, age, sex, month, day, dow,
                                                   user_tab, age_tab, sex_tab, month_tab,
                                                   day_tab, dow_tab, E0);
  k_prep<<<(NL*EMB*160 + NL*EMB + 255)/256, 256, 0, stream>>>(W1, W2, b1, b2, Wt, biasf);

  // ---- CSR build ----
  hipMemsetAsync(rowptr, 0, (N_NODES+1)*sizeof(int), stream);
  k_hist<<<(NNZ+255)/256, 256, 0, stream>>>(lrows, rowptr);
  k_scan1<<<NSCAN_BLOCKS, 256, 0, stream>>>(rowptr, bsum);
  k_scan2<<<1, 512, 0, stream>>>(bsum);
  k_scan3<<<(N_NODES+255)/256, 256, 0, stream>>>(rowptr, bsum, cursor);
  k_scatter_edges<<<(NNZ+255)/256, 256, 0, stream>>>(lrows, lcols, lvals, cursor, cols_s, vals_s);

  // layer-0 slice (raw E0)
  k_gather_wave<<<(3*BATCH+3)/4, 256, 0, stream>>>(E0, u_id, pos, neg, out, 0, 0);

  // ---- layers (ping-pong E0 <-> E1) ----
  float* Ein = E0; float* Eout = E1;
  for (int i = 0; i < NL; i++){
    k_fused<<<(N_NODES+63)/64, 256, 0, stream>>>(Ein, Eout, rowptr, cols_s, vals_s,
                                                 Wt + i*EMB*160, biasf + i*EMB);
    k_gather_wave<<<(3*BATCH+3)/4, 256, 0, stream>>>(Eout, u_id, pos, neg, out, i+1, 1);
    float* t = Ein; Ein = Eout; Eout = t;
  }
}

// Round 8
// 891.650 us; speedup vs baseline: 1.1261x; 1.1261x over previous
//
#include <hip/hip_runtime.h>
#include <hip/hip_bf16.h>

#define N_USER 200000
#define N_ITEM 100000
#define N_NODES 300000
#define EMB 80
#define FEAT 16
#define NL 3
#define NNZ 1000000
#define BATCH 4096
#define OUTW 320

typedef __bf16 bf16x8 __attribute__((ext_vector_type(8)));
typedef float f32x4 __attribute__((ext_vector_type(4)));

__device__ __forceinline__ unsigned short f2bf(float f){
  union { float f; unsigned int i; } x; x.f = f;
  unsigned int i = x.i;
  unsigned int r = i + 0x7fff + ((i >> 16) & 1u);
  return (unsigned short)(r >> 16);
}

// ---- diagnostic fill ----
__global__ void k_fill(float* out, int n, float v){
  int i = blockIdx.x * blockDim.x + threadIdx.x;
  if (i < n) out[i] = v;
}

// ---- winner: last write wins for duplicate u_id ----
__global__ void k_winner(const int* __restrict__ u_id, int* __restrict__ winner){
  int b = blockIdx.x * blockDim.x + threadIdx.x;
  if (b >= BATCH) return;
  atomicMax(&winner[u_id[b]], b);
}

// ---- E = concat(user_tab, item_tab), float4 ----
__global__ void k_copy4(const float4* __restrict__ user_tab, const float4* __restrict__ item_tab,
                        float4* __restrict__ E){
  int idx = blockIdx.x * blockDim.x + threadIdx.x;
  if (idx >= N_NODES*EMB/4) return;
  E[idx] = (idx < N_USER*EMB/4) ? user_tab[idx] : item_tab[idx - N_USER*EMB/4];
}

// ---- blended scatter: E[u_id[b]] = 0.5*(user_tab[u]+feat[b]) for winning b ----
__global__ void k_scatter_blend(const int* __restrict__ u_id, const int* __restrict__ winner,
                        const int* __restrict__ age, const int* __restrict__ sex,
                        const int* __restrict__ month, const int* __restrict__ day,
                        const int* __restrict__ dow,
                        const float* __restrict__ user_tab,
                        const float* __restrict__ age_tab, const float* __restrict__ sex_tab,
                        const float* __restrict__ month_tab, const float* __restrict__ day_tab,
                        const float* __restrict__ dow_tab,
                        float* __restrict__ E){
  int idx = blockIdx.x * blockDim.x + threadIdx.x;
  if (idx >= BATCH*EMB) return;
  int b = idx / EMB;
  int c = idx - b*EMB;
  int u = u_id[b];
  if (winner[u] != b) return;
  int t = c >> 4, cc = c & 15;
  int key; const float* tab;
  switch (t){
    case 0: key = age[b];   tab = age_tab;   break;
    case 1: key = sex[b];   tab = sex_tab;   break;
    case 2: key = month[b]; tab = month_tab; break;
    case 3: key = day[b];   tab = day_tab;   break;
    default: key = dow[b];  tab = dow_tab;   break;
  }
  float f = tab[key*FEAT + cc];
  E[(size_t)u*EMB + c] = 0.5f * user_tab[(size_t)u*EMB + c] + 0.5f * f;
}

// ---- prep: Wt[i][n][k] = stacked [W1;W2]^T (bf16, n-major), biasf = 2*b1+b2 ----
__global__ void k_prep(const float* __restrict__ W1, const float* __restrict__ W2,
                       const float* __restrict__ b1, const float* __restrict__ b2,
                       unsigned short* __restrict__ Wt, float* __restrict__ biasf){
  int idx = blockIdx.x * blockDim.x + threadIdx.x;
  if (idx < NL*EMB*160){
    int i = idx / (EMB*160);
    int rem = idx - i*(EMB*160);
    int n = rem / 160;
    int k = rem - n*160;
    float v = (k < EMB) ? W1[i*EMB*EMB + k*EMB + n] : W2[i*EMB*EMB + (k-EMB)*EMB + n];
    Wt[idx] = f2bf(v);
  } else if (idx < NL*EMB*160 + NL*EMB){
    int t = idx - NL*EMB*160;
    biasf[t] = 2.0f * b1[t] + b2[t];
  }
}

// ================= CSR build =================
__global__ void k_hist(const int* __restrict__ rows, int* __restrict__ cnt){
  int e = blockIdx.x * blockDim.x + threadIdx.x;
  if (e < NNZ) atomicAdd(&cnt[rows[e]], 1);
}

#define SCAN_BLK 1024
__global__ void k_scan1(int* __restrict__ cnt, int* __restrict__ bsum){
  __shared__ int s[256];
  int tid = threadIdx.x;
  int base = blockIdx.x * SCAN_BLK + tid*4;
  int v[4]; int sum = 0;
  #pragma unroll
  for (int j = 0; j < 4; j++){
    int i = base + j;
    v[j] = (i < N_NODES) ? cnt[i] : 0;
    sum += v[j];
  }
  s[tid] = sum; __syncthreads();
  int own = sum;
  for (int d = 1; d < 256; d <<= 1){
    int t = (tid >= d) ? s[tid-d] : 0;
    __syncthreads();
    s[tid] += t;
    __syncthreads();
  }
  int excl = s[tid] - own;
  if (tid == 0) bsum[blockIdx.x] = s[255];
  int run = excl;
  #pragma unroll
  for (int j = 0; j < 4; j++){
    int i = base + j;
    if (i < N_NODES) cnt[i] = run;
    run += v[j];
  }
}

#define NSCAN_BLOCKS ((N_NODES + SCAN_BLK - 1)/SCAN_BLK)   // 293
__global__ void k_scan2(int* __restrict__ bsum){
  __shared__ int s[512];
  int tid = threadIdx.x;
  int v = (tid < NSCAN_BLOCKS) ? bsum[tid] : 0;
  s[tid] = v; __syncthreads();
  for (int d = 1; d < 512; d <<= 1){
    int t = (tid >= d) ? s[tid-d] : 0;
    __syncthreads();
    s[tid] += t;
    __syncthreads();
  }
  if (tid < NSCAN_BLOCKS) bsum[tid] = s[tid] - v;
}

__global__ void k_scan3(int* __restrict__ rowptr, const int* __restrict__ bsum,
                        int* __restrict__ cursor){
  int i = blockIdx.x * blockDim.x + threadIdx.x;
  if (i >= N_NODES) return;
  int v = rowptr[i] + bsum[i >> 10];
  rowptr[i] = v;
  cursor[i] = v;
  if (i == 0) rowptr[N_NODES] = NNZ;
}

__global__ void k_scatter_edges(const int* __restrict__ rows, const int* __restrict__ cols,
                                const float* __restrict__ vals,
                                int* __restrict__ cursor,
                                int* __restrict__ cols_s, float* __restrict__ vals_s){
  int e = blockIdx.x * blockDim.x + threadIdx.x;
  if (e >= NNZ) return;
  int r = rows[e];
  int pos = atomicAdd(&cursor[r], 1);
  cols_s[pos] = cols[e];
  vals_s[pos] = vals[e];
}

// ==== fused layer v2: LE in LDS (only tile); GEMM A-fragments built in registers ====
#define LE_PAD 84   // floats; 336 B row stride -> 2-way bank alias on b128 reads (free)
__launch_bounds__(256)
__global__ void k_fused2(const float* __restrict__ Ein, float* __restrict__ Eout,
                         const int* __restrict__ rowptr, const int* __restrict__ cols_s,
                         const float* __restrict__ vals_s,
                         const unsigned short* __restrict__ Wt, const float* __restrict__ biasf){
  __shared__ float le[64 * LE_PAD];   // 21504 B -> 7 blocks/CU
  int tid = threadIdx.x;
  long row0 = (long)blockIdx.x * 64;

  int lane = tid & 63;
  int wave = tid >> 6;
  int m = lane & 15;
  int quad = lane >> 4;

  // B fragments (Wt n-major) — independent of LDS
  bf16x8 bfrag[5][5];
  #pragma unroll
  for (int nt = 0; nt < 5; nt++)
    #pragma unroll
    for (int kt = 0; kt < 5; kt++)
      bfrag[nt][kt] = *(const bf16x8*)(Wt + (nt*16 + m)*160 + kt*32 + quad*8);

  // phase 1: CSR SpMM rows -> LDS (20 float4-lanes per row)
  for (int u = tid; u < 64*20; u += 256){
    int lr = u / 20, q = u - lr*20;
    long r = row0 + lr;
    float4 acc4 = {0.f,0.f,0.f,0.f};
    if (r < N_NODES){
      int s = rowptr[r], e = rowptr[r+1];
      for (int i = s; i < e; i++){
        int c = cols_s[i];
        float v = vals_s[i];
        const float4 ev = *(const float4*)(Ein + (size_t)c*EMB + q*4);
        acc4.x += v*ev.x; acc4.y += v*ev.y; acc4.z += v*ev.z; acc4.w += v*ev.w;
      }
    }
    *(float4*)(le + lr*LE_PAD + q*4) = acc4;
  }
  __syncthreads();

  // phase 2: K=160 GEMM, A-fragments in registers
  int arow = wave*16 + m;                 // LDS row this lane reads
  long rA = row0 + arow;
  const float* erow = Ein + (size_t)(rA < N_NODES ? rA : 0) * EMB;
  const float* lrow = le + arow*LE_PAD;

  f32x4 acc[5];
  #pragma unroll
  for (int nt = 0; nt < 5; nt++) acc[nt] = (f32x4){0.f,0.f,0.f,0.f};

  #pragma unroll
  for (int kt = 0; kt < 5; kt++){
    int k8 = kt*32 + quad*8;              // 8 consecutive k's; never crosses 80 (80%8==0)
    bool addh = (k8 < EMB);
    int c8 = addh ? k8 : k8 - EMB;
    float4 e0 = *(const float4*)(erow + c8);
    float4 e1 = *(const float4*)(erow + c8 + 4);
    float4 l0 = *(const float4*)(lrow + c8);
    float4 l1 = *(const float4*)(lrow + c8 + 4);
    float x0,x1,x2,x3,x4,x5,x6,x7;
    if (addh){
      x0=e0.x+l0.x; x1=e0.y+l0.y; x2=e0.z+l0.z; x3=e0.w+l0.w;
      x4=e1.x+l1.x; x5=e1.y+l1.y; x6=e1.z+l1.z; x7=e1.w+l1.w;
    } else {
      x0=e0.x*l0.x; x1=e0.y*l0.y; x2=e0.z*l0.z; x3=e0.w*l0.w;
      x4=e1.x*l1.x; x5=e1.y*l1.y; x6=e1.z*l1.z; x7=e1.w*l1.w;
    }
    bf16x8 af;
    af[0]=(__bf16)x0; af[1]=(__bf16)x1; af[2]=(__bf16)x2; af[3]=(__bf16)x3;
    af[4]=(__bf16)x4; af[5]=(__bf16)x5; af[6]=(__bf16)x6; af[7]=(__bf16)x7;
    #pragma unroll
    for (int nt = 0; nt < 5; nt++)
      acc[nt] = __builtin_amdgcn_mfma_f32_16x16x32_bf16(af, bfrag[nt][kt], acc[nt], 0, 0, 0);
  }

  // epilogue: C/D layout col=lane&15, row=quad*4+reg
  long rbase = row0 + wave*16 + quad*4;
  #pragma unroll
  for (int nt = 0; nt < 5; nt++){
    int col = nt*16 + m;
    float b = biasf[col];
    #pragma unroll
    for (int i = 0; i < 4; i++){
      long r = rbase + i;
      if (r < N_NODES){
        float v = acc[nt][i] + b;
        Eout[r*EMB + col] = (v > 0.f) ? v : 0.2f * v;
      }
    }
  }
}

// ---- fused gather + row L2 norm (wave per gathered row), fp32 out ----
__global__ void k_gather_wave(const float* __restrict__ E, const int* __restrict__ u_id,
                              const int* __restrict__ pos, const int* __restrict__ neg,
                              float* __restrict__ out, int layer, int do_norm){
  int gw = blockIdx.x * (blockDim.x >> 6) + (threadIdx.x >> 6);
  if (gw >= 3*BATCH) return;
  int lane = threadIdx.x & 63;
  int chunk = gw / BATCH;
  int b = gw - chunk*BATCH;
  int node = (chunk == 0) ? u_id[b] : ((chunk == 1) ? N_USER + pos[b] : N_USER + neg[b]);
  const float* er = E + (size_t)node*EMB;
  float v0 = er[lane];
  float v1 = (lane < EMB-64) ? er[64 + lane] : 0.f;
  float scale = 1.f;
  if (do_norm){
    float ss = v0*v0 + v1*v1;
    #pragma unroll
    for (int s = 32; s > 0; s >>= 1) ss += __shfl_xor(ss, s, 64);
    float nrm = fmaxf(sqrtf(ss), 1e-12f);
    scale = 1.f / nrm;
  }
  float* po = out + (size_t)chunk*BATCH*OUTW + (size_t)b*OUTW + layer*EMB;
  po[lane] = v0 * scale;
  if (lane < EMB-64) po[64 + lane] = v1 * scale;
}

extern "C" void kernel_launch(void* const* d_in, const int* in_sizes, int n_in,
                              void* d_out, int out_size, void* d_ws, size_t ws_size,
                              hipStream_t stream) {
  float* out = (float*)d_out;

  const size_t OFF_E0     = 0;                   // 96,000,000
  const size_t OFF_E1     = 96000000;            // 96,000,000
  const size_t OFF_ROWPTR = 192000000;           // 1,200,640
  const size_t OFF_CURSOR = 193200640;           // 1,200,640
  const size_t OFF_COLS   = 194401280;           // 4,000,000
  const size_t OFF_VALS   = 198401280;           // 4,000,000
  const size_t OFF_BSUM   = 202401280;           // 4,096
  const size_t OFF_WT     = 202405376;           // 76,800
  const size_t OFF_BIAS   = 202482176;           // 1,024
  const size_t OFF_WIN    = 202483200;           // 800,000
  const size_t NEED       = 203283200;

  float code = 0.f;
  if (ws_size < NEED)                      code = 7.f;
  else if (n_in != 22)                     code = 9.f;
  else if (in_sizes[0] != BATCH)           code = 11.f;
  else if (in_sizes[10] != NNZ)            code = 13.f;
  else if (out_size != 3*BATCH*OUTW)       code = 19.f;
  if (code != 0.f){
    k_fill<<<(out_size + 255)/256, 256, 0, stream>>>(out, out_size, code);
    return;
  }

  const int* u_id  = (const int*)d_in[0];
  const int* age   = (const int*)d_in[1];
  const int* sex   = (const int*)d_in[2];
  const int* month = (const int*)d_in[3];
  const int* day   = (const int*)d_in[4];
  const int* dow   = (const int*)d_in[5];
  const int* pos   = (const int*)d_in[6];
  const int* neg   = (const int*)d_in[7];
  const int* lrows = (const int*)d_in[8];
  const int* lcols = (const int*)d_in[9];
  const float* lvals    = (const float*)d_in[10];
  const float* user_tab = (const float*)d_in[11];
  const float* item_tab = (const float*)d_in[12];
  const float* age_tab  = (const float*)d_in[13];
  const float* sex_tab  = (const float*)d_in[14];
  const float* month_tab= (const float*)d_in[15];
  const float* day_tab  = (const float*)d_in[16];
  const float* dow_tab  = (const float*)d_in[17];
  const float* W1 = (const float*)d_in[18];
  const float* b1 = (const float*)d_in[19];
  const float* W2 = (const float*)d_in[20];
  const float* b2 = (const float*)d_in[21];

  char* ws = (char*)d_ws;
  float* E0     = (float*)(ws + OFF_E0);
  float* E1     = (float*)(ws + OFF_E1);
  int* rowptr   = (int*)(ws + OFF_ROWPTR);
  int* cursor   = (int*)(ws + OFF_CURSOR);
  int* cols_s   = (int*)(ws + OFF_COLS);
  float* vals_s = (float*)(ws + OFF_VALS);
  int* bsum     = (int*)(ws + OFF_BSUM);
  unsigned short* Wt = (unsigned short*)(ws + OFF_WT);
  float* biasf  = (float*)(ws + OFF_BIAS);
  int* winner   = (int*)(ws + OFF_WIN);

  // ---- prologue: build E0 ----
  hipMemsetAsync(winner, 0xFF, N_USER*sizeof(int), stream);
  k_winner<<<(BATCH+255)/256, 256, 0, stream>>>(u_id, winner);
  k_copy4<<<(N_NODES*EMB/4+255)/256, 256, 0, stream>>>((const float4*)user_tab, (const float4*)item_tab, (float4*)E0);
  k_scatter_blend<<<(BATCH*EMB+255)/256, 256, 0, stream>>>(u_id, winner, age, sex, month, day, dow,
                                                   user_tab, age_tab, sex_tab, month_tab,
                                                   day_tab, dow_tab, E0);
  k_prep<<<(NL*EMB*160 + NL*EMB + 255)/256, 256, 0, stream>>>(W1, W2, b1, b2, Wt, biasf);

  // ---- CSR build ----
  hipMemsetAsync(rowptr, 0, (N_NODES+1)*sizeof(int), stream);
  k_hist<<<(NNZ+255)/256, 256, 0, stream>>>(lrows, rowptr);
  k_scan1<<<NSCAN_BLOCKS, 256, 0, stream>>>(rowptr, bsum);
  k_scan2<<<1, 512, 0, stream>>>(bsum);
  k_scan3<<<(N_NODES+255)/256, 256, 0, stream>>>(rowptr, bsum, cursor);
  k_scatter_edges<<<(NNZ+255)/256, 256, 0, stream>>>(lrows, lcols, lvals, cursor, cols_s, vals_s);

  // layer-0 slice (raw E0)
  k_gather_wave<<<(3*BATCH+3)/4, 256, 0, stream>>>(E0, u_id, pos, neg, out, 0, 0);

  // ---- layers (ping-pong E0 <-> E1) ----
  float* Ein = E0; float* Eout = E1;
  for (int i = 0; i < NL; i++){
    k_fused2<<<(N_NODES+63)/64, 256, 0, stream>>>(Ein, Eout, rowptr, cols_s, vals_s,
                                                  Wt + i*EMB*160, biasf + i*EMB);
    k_gather_wave<<<(3*BATCH+3)/4, 256, 0, stream>>>(Eout, u_id, pos, neg, out, i+1, 1);
    float* t = Ein; Ein = Eout; Eout = t;
  }
}